// Round 4
// baseline (4087.848 us; speedup 1.0000x reference)
//
#include <hip/hip_runtime.h>

#define DIM 64
#define UN 8  // pipeline unroll: ring size == step; rows lead 8, indices lead 16

// ---------------------------------------------------------------------------
// h[r][c] = sum_k X[r][k] * W[c][k]   (X: rows x 64, W: 64x64 row-major)
// Thread-per-row, W via wave-uniform addresses -> scalar loads.
// ---------------------------------------------------------------------------
__global__ __launch_bounds__(256) void fc_rows(const float* __restrict__ X,
                                               const float* __restrict__ W,
                                               float* __restrict__ Y,
                                               int nrows) {
    int r = blockIdx.x * blockDim.x + threadIdx.x;
    if (r >= nrows) return;
    const float* x = X + (size_t)r * DIM;
    float4 xv[16];
#pragma unroll
    for (int i = 0; i < 16; ++i)
        xv[i] = reinterpret_cast<const float4*>(x)[i];
    float* y = Y + (size_t)r * DIM;
#pragma unroll 1
    for (int c0 = 0; c0 < DIM; c0 += 4) {
        float out[4];
#pragma unroll
        for (int j = 0; j < 4; ++j) {
            const float* w = W + (size_t)(c0 + j) * DIM;  // uniform address
            float p0 = 0.f, p1 = 0.f, p2 = 0.f, p3 = 0.f;
#pragma unroll
            for (int k = 0; k < 16; ++k) {
                float4 xx = xv[k];
                p0 += xx.x * w[4 * k + 0];
                p1 += xx.y * w[4 * k + 1];
                p2 += xx.z * w[4 * k + 2];
                p3 += xx.w * w[4 * k + 3];
            }
            out[j] = (p0 + p1) + (p2 + p3);
        }
        *reinterpret_cast<float4*>(y + c0) =
            make_float4(out[0], out[1], out[2], out[3]);
    }
}

// ---------------------------------------------------------------------------
// deg[dst[e]]++  (int atomics, 400KB L2-resident)
// ---------------------------------------------------------------------------
__global__ __launch_bounds__(256) void hist(const int* __restrict__ dst,
                                            int* __restrict__ deg, int E) {
    int e = blockIdx.x * blockDim.x + threadIdx.x;
    if (e < E) atomicAdd(&deg[dst[e]], 1);
}

// ---------------------------------------------------------------------------
// Hierarchical scan: (1) per-block inclusive scan + block sums,
// (2) scan of block sums (G <= 1024), (3) add block offsets -> excl scan.
// ---------------------------------------------------------------------------
#define S1_T 1024
__global__ __launch_bounds__(S1_T) void scan1(const int* __restrict__ deg,
                                              int* __restrict__ incl,
                                              int* __restrict__ bsum, int N) {
    __shared__ int buf[2][S1_T];
    int t = threadIdx.x;
    int i = blockIdx.x * S1_T + t;
    int v = (i < N) ? deg[i] : 0;
    buf[0][t] = v;
    __syncthreads();
    int pa = 0;
    for (int off = 1; off < S1_T; off <<= 1) {
        int nv = buf[pa][t] + ((t >= off) ? buf[pa][t - off] : 0);
        __syncthreads();
        buf[pa ^ 1][t] = nv;
        __syncthreads();
        pa ^= 1;
    }
    if (i < N) incl[i] = buf[pa][t];
    if (t == S1_T - 1) bsum[blockIdx.x] = buf[pa][t];
}

__global__ __launch_bounds__(1024) void scan2(const int* __restrict__ bsum,
                                              int* __restrict__ boff, int G) {
    __shared__ int buf[2][1024];
    int t = threadIdx.x;
    int v = (t < G) ? bsum[t] : 0;
    buf[0][t] = v;
    __syncthreads();
    int pa = 0;
    for (int off = 1; off < 1024; off <<= 1) {
        int nv = buf[pa][t] + ((t >= off) ? buf[pa][t - off] : 0);
        __syncthreads();
        buf[pa ^ 1][t] = nv;
        __syncthreads();
        pa ^= 1;
    }
    if (t < G) boff[t] = buf[pa][t] - v;  // exclusive
}

__global__ __launch_bounds__(256) void scan3(const int* __restrict__ deg,
                                             const int* __restrict__ incl,
                                             const int* __restrict__ boff,
                                             int* __restrict__ offsets,
                                             int* __restrict__ cursor, int N) {
    int i = blockIdx.x * blockDim.x + threadIdx.x;
    if (i < N) {
        int ex = incl[i] - deg[i] + boff[i >> 10];
        offsets[i] = ex;
        cursor[i] = ex;
    }
}

// ---------------------------------------------------------------------------
// CSR build: slot p = cursor[dst]++ ; es[p] = (edge, src)
// ---------------------------------------------------------------------------
__global__ __launch_bounds__(256) void scatter(const int* __restrict__ src,
                                               const int* __restrict__ dst,
                                               int* __restrict__ cursor,
                                               int2* __restrict__ es, int E) {
    int e = blockIdx.x * blockDim.x + threadIdx.x;
    if (e < E) {
        int d = dst[e];
        int p = atomicAdd(&cursor[d], 1);
        es[p] = make_int2(e, src[e]);
    }
}

// ---------------------------------------------------------------------------
// Wave per node, lane = channel c. 8-deep pipeline, ring size == unroll step:
//   invariant at iteration j, slot u: xb/zb[u] = rows of edge j+u,
//                                     eb[u]    = (edge,src) of edge j+u+8.
//   body: consume rows(j+u); row-load edge j+u+8 from eb[u]; eb[u] <- idx j+u+16.
//   All ring indices are the compile-time constant u (rule #20: no scratch).
// Per edge: eh[c] = dot(edge_h[e], W_fcr[c]) via LDS-broadcast of edge row
// against per-lane W row (64 VGPRs); ex=exp(eh); num += ex*(h[src][c]+eh);
// den += ex. Epilogue: relu(num/den + (h[n] @ loop_W)[c]) or relu(h[n][c]).
// No max-subtraction: softmax is shift-invariant, eh ~ N(0,1).
// ---------------------------------------------------------------------------
__global__ __launch_bounds__(256) void reduce_nodes(
    const float* __restrict__ EH, const float* __restrict__ H,
    const float* __restrict__ Wr, const float* __restrict__ LW,
    const int* __restrict__ offsets, const int* __restrict__ deg,
    const int2* __restrict__ es, float* __restrict__ out, int N) {
    __shared__ float xrow[4][DIM];
    int wid = threadIdx.x >> 6;
    int lane = threadIdx.x & 63;
    int n = blockIdx.x * 4 + wid;
    if (n >= N) return;
    float* myx = xrow[wid];

    // per-lane W_fcr row (channel = lane): 64 VGPRs
    float wr[DIM];
#pragma unroll
    for (int k4 = 0; k4 < 16; ++k4) {
        float4 w =
            *reinterpret_cast<const float4*>(Wr + (size_t)lane * DIM + 4 * k4);
        wr[4 * k4 + 0] = w.x;
        wr[4 * k4 + 1] = w.y;
        wr[4 * k4 + 2] = w.z;
        wr[4 * k4 + 3] = w.w;
    }

    int start = offsets[n];
    int cnt = deg[n];
    float num = 0.f, den = 0.f;

    int2 eb[UN];  // index ring: edge j+u+UN
    float xb[UN], zb[UN];

    // prologue: rows of edges 0..7 (direct index load), eb = indices 8..15
#pragma unroll
    for (int u = 0; u < UN; ++u) {
        if (u < cnt) {
            int2 q = es[start + u];
            xb[u] = EH[(size_t)q.x * DIM + lane];
            zb[u] = H[(size_t)q.y * DIM + lane];
        }
    }
#pragma unroll
    for (int u = 0; u < UN; ++u)
        if (u + UN < cnt) eb[u] = es[start + u + UN];

    int j = 0;
    for (; j + UN <= cnt; j += UN) {
#pragma unroll
        for (int u = 0; u < UN; ++u) {
            float xv = xb[u], z = zb[u];
            int ridx = j + u + UN;
            if (ridx < cnt) {  // rows for edge j+u+8 (index resident in eb[u])
                int2 q = eb[u];
                xb[u] = EH[(size_t)q.x * DIM + lane];
                zb[u] = H[(size_t)q.y * DIM + lane];
            }
            int iidx = j + u + 2 * UN;
            if (iidx < cnt) eb[u] = es[start + iidx];  // index for j+u+16
            // compute edge j+u
            myx[lane] = xv;
            asm volatile("s_waitcnt lgkmcnt(0)" ::: "memory");
            float eh = 0.f;
#pragma unroll
            for (int k4 = 0; k4 < 16; ++k4) {
                float4 x4 = *reinterpret_cast<const float4*>(myx + 4 * k4);
                eh += x4.x * wr[4 * k4 + 0];
                eh += x4.y * wr[4 * k4 + 1];
                eh += x4.z * wr[4 * k4 + 2];
                eh += x4.w * wr[4 * k4 + 3];
            }
            float ex = __expf(eh);
            num += ex * (z + eh);
            den += ex;
        }
    }
    // tail: xb/zb[u] hold rows of edges j+u (prefetched by last iteration
    // or the prologue when cnt < 8)
#pragma unroll
    for (int u = 0; u < UN; ++u) {
        if (j + u < cnt) {
            float xv = xb[u], z = zb[u];
            myx[lane] = xv;
            asm volatile("s_waitcnt lgkmcnt(0)" ::: "memory");
            float eh = 0.f;
#pragma unroll
            for (int k4 = 0; k4 < 16; ++k4) {
                float4 x4 = *reinterpret_cast<const float4*>(myx + 4 * k4);
                eh += x4.x * wr[4 * k4 + 0];
                eh += x4.y * wr[4 * k4 + 1];
                eh += x4.z * wr[4 * k4 + 2];
                eh += x4.w * wr[4 * k4 + 3];
            }
            float ex = __expf(eh);
            num += ex * (z + eh);
            den += ex;
        }
    }

    float hval = H[(size_t)n * DIM + lane];
    float res;
    if (cnt > 0) {
        myx[lane] = hval;
        asm volatile("s_waitcnt lgkmcnt(0)" ::: "memory");
        float loop = 0.f;
#pragma unroll
        for (int k4 = 0; k4 < 16; ++k4) {
            float4 x4 = *reinterpret_cast<const float4*>(myx + 4 * k4);
            loop += x4.x * LW[(4 * k4 + 0) * DIM + lane];  // coalesced, L1-hit
            loop += x4.y * LW[(4 * k4 + 1) * DIM + lane];
            loop += x4.z * LW[(4 * k4 + 2) * DIM + lane];
            loop += x4.w * LW[(4 * k4 + 3) * DIM + lane];
        }
        res = num / den + loop;
    } else {
        res = hval;
    }
    out[(size_t)n * DIM + lane] = fmaxf(res, 0.f);
}

extern "C" void kernel_launch(void* const* d_in, const int* in_sizes, int n_in,
                              void* d_out, int out_size, void* d_ws,
                              size_t ws_size, hipStream_t stream) {
    const float* node_h = (const float*)d_in[0];
    const float* edge_h = (const float*)d_in[1];
    const int* src = (const int*)d_in[2];
    const int* dst = (const int*)d_in[3];
    const float* W_fc = (const float*)d_in[4];
    const float* W_fcr = (const float*)d_in[5];
    const float* loop_W = (const float*)d_in[6];

    const int N = in_sizes[0] / DIM;
    const int E = in_sizes[1] / DIM;

    float* out = (float*)d_out;

    // workspace layout (~40 MB; >=51.2 MB proven available in R1)
    float* h = (float*)d_ws;                 // N*64 f32
    int* deg = (int*)(h + (size_t)N * DIM);  // N
    int* offsets = deg + N;                  // N
    int* cursor = offsets + N;               // N
    int* incl = cursor + N;                  // N
    int* bsum = incl + N;                    // 1024
    int* boff = bsum + 1024;                 // 1024
    int2* es = (int2*)(boff + 1024);         // E int2

    hipMemsetAsync(deg, 0, (size_t)N * sizeof(int), stream);

    fc_rows<<<(N + 255) / 256, 256, 0, stream>>>(node_h, W_fc, h, N);
    hist<<<(E + 255) / 256, 256, 0, stream>>>(dst, deg, E);
    int G = (N + S1_T - 1) / S1_T;
    scan1<<<G, S1_T, 0, stream>>>(deg, incl, bsum, N);
    scan2<<<1, 1024, 0, stream>>>(bsum, boff, G);
    scan3<<<(N + 255) / 256, 256, 0, stream>>>(deg, incl, boff, offsets, cursor,
                                               N);
    scatter<<<(E + 255) / 256, 256, 0, stream>>>(src, dst, cursor, es, E);
    reduce_nodes<<<(N + 3) / 4, 256, 0, stream>>>(edge_h, h, W_fcr, loop_W,
                                                  offsets, deg, es, out, N);
}